// Round 10
// baseline (355.845 us; speedup 1.0000x reference)
//
#include <hip/hip_runtime.h>
#include <hip/hip_bf16.h>
#include <cstdint>

typedef unsigned short u16;
typedef __attribute__((ext_vector_type(8))) __bf16 bf16x8;
typedef __attribute__((ext_vector_type(4))) float f32x4;
typedef __attribute__((ext_vector_type(8))) u16 us8;
typedef __attribute__((ext_vector_type(4))) u16 us4;

__device__ __forceinline__ float bf2f(u16 u) {
    return __uint_as_float(((unsigned int)u) << 16);
}
__device__ __forceinline__ u16 f2bf(float f) {
    unsigned int u = __float_as_uint(f);
    unsigned int r = (u + 0x7fffu + ((u >> 16) & 1u)) >> 16;
    return (u16)r;
}

__device__ __forceinline__ void gload_lds16(const void* src, void* dst) {
    __builtin_amdgcn_global_load_lds(
        (const __attribute__((address_space(1))) void*)src,
        (__attribute__((address_space(3))) void*)dst,
        16, 0, 0);
}

// ---------------------------------------------------------------------------
// Weight prep (bf16, transposed: BT[n][k] contiguous along K):
//  BT1 (1024x512): rows j<512 = mW1_top^T ; rows j>=512 = mW1_bot^T
//  BT4 (512x512)  = uW2^T
//  A_w (512x512)  : A_w[j][l] = uW1[512+l][j]   (GEMM-A for Wc^T)
//  B_w (512x512)  : mW2 as-is
//  BTx (512x1024) : k<512 = uW1_top^T; k>=512 = Wc^T (filled by wc gemm)
//  bias1024       : [mb1 | 0]
// ---------------------------------------------------------------------------
__global__ void prep_weights(const float* __restrict__ mW1, const float* __restrict__ mW2,
                             const float* __restrict__ uW1, const float* __restrict__ uW2,
                             const float* __restrict__ mb1,
                             u16* __restrict__ BT1, u16* __restrict__ BT4,
                             u16* __restrict__ A_w, u16* __restrict__ B_w,
                             u16* __restrict__ BTx, float* __restrict__ bias1024)
{
    int tid = blockIdx.x * 256 + threadIdx.x;           // [0, 524288)
    if (tid < 1024 * 512) {
        int j = tid >> 9, k = tid & 511;
        float v = (j < 512) ? mW1[(size_t)k * 512 + j]
                            : mW1[(size_t)(512 + k) * 512 + (j - 512)];
        BT1[tid] = f2bf(v);
    }
    if (tid < 512 * 512) {
        int j = tid >> 9, k = tid & 511;
        BT4[tid] = f2bf(uW2[(size_t)k * 512 + j]);
        A_w[tid] = f2bf(uW1[(size_t)(512 + k) * 512 + j]);
        B_w[tid] = f2bf(mW2[tid]);
        BTx[(size_t)j * 1024 + k] = f2bf(uW1[(size_t)k * 512 + j]);
    }
    if (tid < 1024) bias1024[tid] = (tid < 512) ? mb1[tid] : 0.f;
}

// biasx[j] = ub1[j] + sum_l mb2[l] * uW1[512+l][j]   (one wave per j)
__global__ void prep_biasx(const float* __restrict__ ub1, const float* __restrict__ mb2,
                           const float* __restrict__ uW1, float* __restrict__ biasx)
{
    int wv = threadIdx.x >> 6, lane = threadIdx.x & 63;
    int j = blockIdx.x * 4 + wv;
    if (j >= 512) return;
    float s = 0.f;
    for (int l = lane; l < 512; l += 64)
        s += mb2[l] * uW1[(size_t)(512 + l) * 512 + j];
#pragma unroll
    for (int off = 32; off; off >>= 1) s += __shfl_xor(s, off, 64);
    if (lane == 0) biasx[j] = ub1[j] + s;
}

// Cast x (f32, M x 512) into cols [0,512) of XS (bf16, M x 1024)
__global__ void cast_x(const float* __restrict__ x, u16* __restrict__ XS, int total4)
{
    int i = blockIdx.x * 256 + threadIdx.x;
    if (i >= total4) return;
    int r = i >> 7, cg = i & 127;
    float4 v = ((const float4*)x)[i];
    us4 o = { f2bf(v.x), f2bf(v.y), f2bf(v.z), f2bf(v.w) };
    *(us4*)(XS + (size_t)r * 1024 + cg * 4) = o;
}

// ---------------------------------------------------------------------------
// 256x256 deep-pipelined GEMM: C[M,N] = A[M,K] @ BT[N][K].
// R9 hit the 2-phase ceiling (584 TF ~ m233's 607); this is the 256^2/BK=64
// structure with K-tile-granular double buffer + counted vmcnt:
//  - 8 waves (2M x 4N); wave owns 128x64; acc[8][4] f32x4 = 128 VGPR.
//  - LDS = 2 bufs x (A 32KB + B 32KB) = 128 KB; buffer parity = t&1.
//  - Per K-tile t: read ALL 24 fragments -> regs; lgkm(0)+barrier (buf p
//    consumed); stage tile t+2 into p; vmcnt(8)+barrier (tile t+1 landed,
//    t+2's 8 loads stay in flight -- never drained mid-loop); 64 MFMA.
//    Race-free by construction.
//  - Row-local XOR swizzle (R9-verified-zero-conflict family, re-derived for
//    8 chunks/row): source chunk (tid&7)^((tid>>3)&7) keeps each 8-lane
//    group inside one 128B row segment (coalescing intact); read slot
//    (s*4+h)^(lr&7) spreads 16-lane fragment reads uniformly over banks.
// ---------------------------------------------------------------------------
template<int OUTF32, int DOSILU, int DOBIAS, int DORES>
__global__ __launch_bounds__(512, 1)
void gemm_bt(const u16* __restrict__ A, int lda,
             const u16* __restrict__ Bt, int ldb,
             u16* __restrict__ Cb, float* __restrict__ Cf, int ldc,
             const float* __restrict__ bias,
             const u16* __restrict__ xres, const float* __restrict__ lat,
             const float* __restrict__ ub2v, int Nn, int M, int K)
{
    __shared__ __align__(16) u16 lds[2][2][16384];   // [buf][A/B][32KB]

    // T1: XCD-chunked bijective remap (m204)
    const int gx  = gridDim.x;
    const int nwg = gx * (int)gridDim.y;
    int flat = blockIdx.y * gx + blockIdx.x;
    {
        int q = nwg >> 3, r = nwg & 7;
        int xcd = flat & 7, jj = flat >> 3;
        flat = (xcd < r ? xcd * (q + 1) : r * (q + 1) + (xcd - r) * q) + jj;
    }
    const int m0 = (flat / gx) * 256;
    const int n0 = (flat % gx) * 256;

    const int tid  = threadIdx.x;
    const int wid  = tid >> 6;          // 0..7
    const int lane = tid & 63;
    const int lr   = lane & 15;
    const int h    = lane >> 4;
    const int wr   = wid >> 2;          // 0..1  M half
    const int wc   = wid & 3;           // 0..3  N quarter
    const int sl   = lr & 7;            // read-side swizzle key

    f32x4 acc[8][4];
#pragma unroll
    for (int i = 0; i < 8; ++i)
#pragma unroll
        for (int j = 0; j < 4; ++j)
            acc[i][j] = (f32x4){0.f, 0.f, 0.f, 0.f};

    const int KT = K >> 6;              // K-tiles of 64 (>= 8 for all calls)

    // staging: 8 gload_lds16/thread per K-tile (4 A + 4 B), each covers 8KB.
    // thread -> LDS row (l*64 + tid>>3), chunk tid&7 (linear dest);
    // global chunk = (tid&7) ^ ((tid>>3)&7)  (row-local permute).
    const int trow = tid >> 3;                       // 0..63
    const int gch  = (tid & 7) ^ (trow & 7);

    auto stage = [&](int t, int p) {
        const int k0 = t << 6;
#pragma unroll
        for (int l = 0; l < 4; ++l) {
            int ga = m0 + l * 64 + trow; ga = ga < M ? ga : M - 1;
            gload_lds16(A + (size_t)ga * lda + k0 + gch * 8,
                        &lds[p][0][l * 4096 + tid * 8]);
        }
#pragma unroll
        for (int l = 0; l < 4; ++l) {
            int gb = n0 + l * 64 + trow;
            gload_lds16(Bt + (size_t)gb * ldb + k0 + gch * 8,
                        &lds[p][1][l * 4096 + tid * 8]);
        }
    };

    // prologue: tiles 0,1 in flight; gate tile 0
    stage(0, 0);
    stage(1, 1);
    asm volatile("s_waitcnt vmcnt(8)" ::: "memory");
    __builtin_amdgcn_sched_barrier(0);
    __builtin_amdgcn_s_barrier();

    for (int t = 0; t < KT; ++t) {
        const int p = t & 1;
        const u16* baseA = &lds[p][0][0];
        const u16* baseB = &lds[p][1][0];

        // phase 1: ALL fragments of tile t -> registers (24 x ds_read_b128)
        bf16x8 af[8][2], bfv[4][2];
#pragma unroll
        for (int i = 0; i < 8; ++i) {
            int row = wr * 128 + i * 16 + lr;
#pragma unroll
            for (int s = 0; s < 2; ++s)
                af[i][s] = *(const bf16x8*)&baseA[row * 64 + ((s * 4 + h) ^ sl) * 8];
        }
#pragma unroll
        for (int j = 0; j < 4; ++j) {
            int row = wc * 64 + j * 16 + lr;
#pragma unroll
            for (int s = 0; s < 2; ++s)
                bfv[j][s] = *(const bf16x8*)&baseB[row * 64 + ((s * 4 + h) ^ sl) * 8];
        }

        // phase 2: buffer handoff (counted vmcnt -- loads span iterations)
        if (t + 2 < KT) {
            asm volatile("s_waitcnt lgkmcnt(0)" ::: "memory");  // my reads retired
            __builtin_amdgcn_sched_barrier(0);
            __builtin_amdgcn_s_barrier();                       // buf p free
            stage(t + 2, p);
            asm volatile("s_waitcnt vmcnt(8)" ::: "memory");    // tile t+1 landed
            __builtin_amdgcn_sched_barrier(0);
            __builtin_amdgcn_s_barrier();
        } else if (t + 1 < KT) {
            asm volatile("s_waitcnt vmcnt(0)" ::: "memory");    // tile t+1 landed
            __builtin_amdgcn_sched_barrier(0);
            __builtin_amdgcn_s_barrier();
        }

        // phase 3: 64 MFMA on registers
#pragma unroll
        for (int s = 0; s < 2; ++s)
#pragma unroll
            for (int i = 0; i < 8; ++i)
#pragma unroll
                for (int j = 0; j < 4; ++j)
                    acc[i][j] = __builtin_amdgcn_mfma_f32_16x16x32_bf16(
                        af[i][s], bfv[j][s], acc[i][j], 0, 0, 0);
    }

    float bb[4];
#pragma unroll
    for (int j = 0; j < 4; ++j)
        bb[j] = DOBIAS ? bias[n0 + wc * 64 + j * 16 + lr] : 0.f;

    // D layout (m89-verified): col = lane&15, row = 4*(lane>>4) + reg
#pragma unroll
    for (int i = 0; i < 8; ++i) {
#pragma unroll
        for (int rj = 0; rj < 4; ++rj) {
            int grow = m0 + wr * 128 + i * 16 + 4 * h + rj;
            if (grow >= M) continue;
            size_t ro = (size_t)grow * ldc;
            size_t xo = 0, lo = 0;
            if (DORES) {
                int nn = grow % Nn;
                xo = (size_t)grow * 1024;      // XS row (bf16 x in cols 0..511)
                lo = (size_t)nn * 512;
            }
#pragma unroll
            for (int j = 0; j < 4; ++j) {
                int gcol = n0 + wc * 64 + j * 16 + lr;
                float v = acc[i][j][rj] + bb[j];
                if (DOSILU) v = v * __builtin_amdgcn_rcpf(1.f + __expf(-v));
                if (DORES)
                    v += bf2f(xres[xo + gcol]) + lat[lo + gcol] + ub2v[gcol];
                if (OUTF32) Cf[ro + gcol] = v;
                else        Cb[ro + gcol] = f2bf(v);
            }
        }
    }
}

// ---------------------------------------------------------------------------
// S[row] = (1/8) * sum_k silu(c_projb[row] + n_proj[b, knn[n,k]])
// (mb1 folded into c_proj via G1 bias.)  Writes cols 512.. of XS.
// ---------------------------------------------------------------------------
__global__ void gather_silu_mean(const u16* __restrict__ P, const int* __restrict__ knn,
                                 u16* __restrict__ XS, int Nn, int M)
{
    int wid = threadIdx.x >> 6, lane = threadIdx.x & 63;
    int row = blockIdx.x * 4 + wid;
    if (row >= M) return;
    int b = row / Nn, n = row - b * Nn;
    int c0 = lane * 8;

    int idx[8];
#pragma unroll
    for (int k = 0; k < 8; ++k) idx[k] = knn[n * 8 + k];

    us8 cu = *(const us8*)(P + (size_t)row * 1024 + c0);
    const u16* Pn = P + (size_t)b * Nn * 1024 + 512 + c0;
    us8 nb[8];
#pragma unroll
    for (int k = 0; k < 8; ++k) nb[k] = *(const us8*)(Pn + (size_t)idx[k] * 1024);

    float base[8], accv[8];
#pragma unroll
    for (int i = 0; i < 8; ++i) { base[i] = bf2f(cu[i]); accv[i] = 0.f; }

#pragma unroll
    for (int k = 0; k < 8; ++k)
#pragma unroll
        for (int i = 0; i < 8; ++i) {
            float pv = base[i] + bf2f(nb[k][i]);
            accv[i] += pv * __builtin_amdgcn_rcpf(1.f + __expf(-pv));
        }

    us8 o;
#pragma unroll
    for (int i = 0; i < 8; ++i) o[i] = f2bf(accv[i] * 0.125f);
    *(us8*)(XS + (size_t)row * 1024 + 512 + c0) = o;
}

// ---------------------------------------------------------------------------
// LN only (residual already added by G4 epilogue): Y = LN(Y)*g + b, in place.
// ---------------------------------------------------------------------------
__global__ void ln_fuse(float* __restrict__ Y, const float* __restrict__ g,
                        const float* __restrict__ bta, int M)
{
    int wid = threadIdx.x >> 6, lane = threadIdx.x & 63;
    int row = blockIdx.x * 4 + wid;
    if (row >= M) return;
    int c0 = lane * 8;

    float* yr = Y + (size_t)row * 512 + c0;
    float v[8];
#pragma unroll
    for (int i = 0; i < 8; ++i) v[i] = yr[i];

    float s = 0.f;
#pragma unroll
    for (int i = 0; i < 8; ++i) s += v[i];
#pragma unroll
    for (int off = 32; off > 0; off >>= 1) s += __shfl_xor(s, off, 64);
    float mu = s * (1.f / 512.f);

    float q = 0.f;
#pragma unroll
    for (int i = 0; i < 8; ++i) { float d = v[i] - mu; q += d * d; }
#pragma unroll
    for (int off = 32; off > 0; off >>= 1) q += __shfl_xor(q, off, 64);
    float inv = rsqrtf(q * (1.f / 512.f) + 1e-5f);

#pragma unroll
    for (int i = 0; i < 8; ++i) yr[i] = (v[i] - mu) * inv * g[c0 + i] + bta[c0 + i];
}

extern "C" void kernel_launch(void* const* d_in, const int* in_sizes, int n_in,
                              void* d_out, int out_size, void* d_ws, size_t ws_size,
                              hipStream_t stream)
{
    const float* x   = (const float*)d_in[0];
    const float* lat = (const float*)d_in[1];
    const int*   knn = (const int*)d_in[2];
    const float* mW1 = (const float*)d_in[3];
    const float* mb1 = (const float*)d_in[4];
    const float* mW2 = (const float*)d_in[5];
    const float* mb2 = (const float*)d_in[6];
    const float* uW1 = (const float*)d_in[7];
    const float* ub1 = (const float*)d_in[8];
    const float* uW2 = (const float*)d_in[9];
    const float* ub2 = (const float*)d_in[10];
    const float* lng = (const float*)d_in[11];
    const float* lnb = (const float*)d_in[12];

    const int Nn = 10242;
    const int M  = 4 * Nn;       // 40968

    char* ws = (char*)d_ws;
    u16* BT1 = (u16*)ws; ws += (size_t)1024 * 512 * 2;
    u16* BTx = (u16*)ws; ws += (size_t)512 * 1024 * 2;
    u16* BT4 = (u16*)ws; ws += (size_t)512 * 512 * 2;
    u16* A_w = (u16*)ws; ws += (size_t)512 * 512 * 2;
    u16* B_w = (u16*)ws; ws += (size_t)512 * 512 * 2;
    float* bias1024 = (float*)ws; ws += 1024 * 4;
    float* biasx    = (float*)ws; ws += 512 * 4;
    u16* XS = (u16*)ws; ws += (size_t)M * 1024 * 2;    // [x_bf16 | S]
    u16* P  = (u16*)ws; ws += (size_t)M * 1024 * 2;    // [c_proj+mb1 | n_proj]
    u16* T  = (u16*)ws; ws += (size_t)M * 512 * 2;     // silu(u-pre)
    float* Y = (float*)d_out;

    const int MB = (M + 255) / 256;  // 161

    prep_weights<<<2048, 256, 0, stream>>>(mW1, mW2, uW1, uW2, mb1,
                                           BT1, BT4, A_w, B_w, BTx, bias1024);
    prep_biasx<<<128, 256, 0, stream>>>(ub1, mb2, uW1, biasx);
    cast_x<<<(M * 512 / 4 + 255) / 256, 256, 0, stream>>>(x, XS, M * 512 / 4);

    // Wc^T -> BTx cols 512..1023  (M=512, N=512, K=512)
    gemm_bt<0, 0, 0, 0><<<dim3(2, 2), 512, 0, stream>>>(
        A_w, 512, B_w, 512, BTx + 512, nullptr, 1024,
        nullptr, nullptr, nullptr, nullptr, 0, 512, 512);

    // G1: P = x @ [mW1_top | mW1_bot] + [mb1 | 0]   (M x 1024, K=512)
    gemm_bt<0, 0, 1, 0><<<dim3(4, MB), 512, 0, stream>>>(
        XS, 1024, BT1, 512, P, nullptr, 1024,
        bias1024, nullptr, nullptr, nullptr, 0, M, 512);

    gather_silu_mean<<<(M + 3) / 4, 256, 0, stream>>>(P, knn, XS, Nn, M);

    // Gx: T = silu([x|S] @ [uW1_top; Wc] + biasx)   (M x 512, K=1024)
    gemm_bt<0, 1, 1, 0><<<dim3(2, MB), 512, 0, stream>>>(
        XS, 1024, BTx, 1024, T, nullptr, 512,
        biasx, nullptr, nullptr, nullptr, 0, M, 1024);

    // G4: Y = T @ uW2 + bf16(x) + lat + ub2   (f32 out; LN separate)
    gemm_bt<1, 0, 0, 1><<<dim3(2, MB), 512, 0, stream>>>(
        T, 512, BT4, 512, nullptr, Y, 512,
        nullptr, XS, lat, ub2, Nn, M, 512);

    ln_fuse<<<(M + 3) / 4, 256, 0, stream>>>(Y, lng, lnb, M);
}

// Round 11
// 309.021 us; speedup vs baseline: 1.1515x; 1.1515x over previous
//
#include <hip/hip_runtime.h>
#include <hip/hip_bf16.h>
#include <cstdint>

typedef unsigned short u16;
typedef __attribute__((ext_vector_type(8))) __bf16 bf16x8;
typedef __attribute__((ext_vector_type(4))) float f32x4;
typedef __attribute__((ext_vector_type(8))) u16 us8;
typedef __attribute__((ext_vector_type(4))) u16 us4;

__device__ __forceinline__ float bf2f(u16 u) {
    return __uint_as_float(((unsigned int)u) << 16);
}
__device__ __forceinline__ u16 f2bf(float f) {
    unsigned int u = __float_as_uint(f);
    unsigned int r = (u + 0x7fffu + ((u >> 16) & 1u)) >> 16;
    return (u16)r;
}

__device__ __forceinline__ void gload_lds16(const void* src, void* dst) {
    __builtin_amdgcn_global_load_lds(
        (const __attribute__((address_space(1))) void*)src,
        (__attribute__((address_space(3))) void*)dst,
        16, 0, 0);
}

// ---------------------------------------------------------------------------
// Weight prep (bf16, transposed: BT[n][k] contiguous along K):
//  BT1 (1024x512): rows j<512 = mW1_top^T ; rows j>=512 = mW1_bot^T
//  BT4 (512x512)  = uW2^T
//  A_w (512x512)  : A_w[j][l] = uW1[512+l][j]   (GEMM-A for Wc^T)
//  B_w (512x512)  : mW2 as-is
//  BTx (512x1024) : k<512 = uW1_top^T; k>=512 = Wc^T (filled by wc gemm)
//  bias1024       : [mb1 | 0]
// ---------------------------------------------------------------------------
__global__ void prep_weights(const float* __restrict__ mW1, const float* __restrict__ mW2,
                             const float* __restrict__ uW1, const float* __restrict__ uW2,
                             const float* __restrict__ mb1,
                             u16* __restrict__ BT1, u16* __restrict__ BT4,
                             u16* __restrict__ A_w, u16* __restrict__ B_w,
                             u16* __restrict__ BTx, float* __restrict__ bias1024)
{
    int tid = blockIdx.x * 256 + threadIdx.x;           // [0, 524288)
    if (tid < 1024 * 512) {
        int j = tid >> 9, k = tid & 511;
        float v = (j < 512) ? mW1[(size_t)k * 512 + j]
                            : mW1[(size_t)(512 + k) * 512 + (j - 512)];
        BT1[tid] = f2bf(v);
    }
    if (tid < 512 * 512) {
        int j = tid >> 9, k = tid & 511;
        BT4[tid] = f2bf(uW2[(size_t)k * 512 + j]);
        A_w[tid] = f2bf(uW1[(size_t)(512 + k) * 512 + j]);
        B_w[tid] = f2bf(mW2[tid]);
        BTx[(size_t)j * 1024 + k] = f2bf(uW1[(size_t)k * 512 + j]);
    }
    if (tid < 1024) bias1024[tid] = (tid < 512) ? mb1[tid] : 0.f;
}

// biasx[j] = ub1[j] + sum_l mb2[l] * uW1[512+l][j]   (one wave per j)
__global__ void prep_biasx(const float* __restrict__ ub1, const float* __restrict__ mb2,
                           const float* __restrict__ uW1, float* __restrict__ biasx)
{
    int wv = threadIdx.x >> 6, lane = threadIdx.x & 63;
    int j = blockIdx.x * 4 + wv;
    if (j >= 512) return;
    float s = 0.f;
    for (int l = lane; l < 512; l += 64)
        s += mb2[l] * uW1[(size_t)(512 + l) * 512 + j];
#pragma unroll
    for (int off = 32; off; off >>= 1) s += __shfl_xor(s, off, 64);
    if (lane == 0) biasx[j] = ub1[j] + s;
}

// Cast x (f32, M x 512) into cols [0,512) of XS (bf16, M x 1024)
__global__ void cast_x(const float* __restrict__ x, u16* __restrict__ XS, int total4)
{
    int i = blockIdx.x * 256 + threadIdx.x;
    if (i >= total4) return;
    int r = i >> 7, cg = i & 127;
    float4 v = ((const float4*)x)[i];
    us4 o = { f2bf(v.x), f2bf(v.y), f2bf(v.z), f2bf(v.w) };
    *(us4*)(XS + (size_t)r * 1024 + cg * 4) = o;
}

// ---------------------------------------------------------------------------
// GEMM: C[M,N] = A[M,K] (bf16, lda) @ BT[N][K] (bf16, ldb)
// R9 base (best: 73.5us/GEMM, 0 conflicts) with ONE structural change:
// SINGLE barrier per K-step. With triple buffering the old lgkm(0)+barrier-2
// is redundant: the buffer staged at step t ((t+2)%3 = (t-1)%3) had its
// ds_reads consumed by step t-1's MFMAs -- the compiler's lgkmcnt-before-MFMA
// guarantees retirement before any wave reaches step t's barrier.
// Step: vmcnt(4) [tile t landed, t+1 flying] -> barrier -> stage(t+2)
//       -> ds_read frags -> 16 MFMA.
// Row-local XOR swizzle (R9-verified: 0 conflicts, coalescing intact).
// ---------------------------------------------------------------------------
template<int OUTF32, int DOSILU, int DOBIAS, int DORES>
__global__ __launch_bounds__(256, 3)
void gemm_bt(const u16* __restrict__ A, int lda,
             const u16* __restrict__ Bt, int ldb,
             u16* __restrict__ Cb, float* __restrict__ Cf, int ldc,
             const float* __restrict__ bias,
             const u16* __restrict__ xres, const float* __restrict__ lat,
             const float* __restrict__ ub2v, int Nn, int M, int K)
{
    __shared__ __align__(16) u16 lA[3][128 * 32];   // 3 x 8 KB
    __shared__ __align__(16) u16 lB[3][128 * 32];   // 3 x 8 KB

    // T1: XCD-chunked bijective remap (m204)
    const int gx  = gridDim.x;
    const int nwg = gx * (int)gridDim.y;
    int flat = blockIdx.y * gx + blockIdx.x;
    {
        int q = nwg >> 3, r = nwg & 7;
        int xcd = flat & 7, jj = flat >> 3;
        flat = (xcd < r ? xcd * (q + 1) : r * (q + 1) + (xcd - r) * q) + jj;
    }
    const int m0 = (flat / gx) * 128;
    const int n0 = (flat % gx) * 128;

    const int tid  = threadIdx.x;
    const int wid  = tid >> 6;
    const int lane = tid & 63;
    const int lr   = lane & 15;
    const int h    = lane >> 4;
    const int wm   = (wid >> 1) * 64;
    const int wn   = (wid & 1) * 64;
    const int sw   = (lr >> 1) & 3;     // read-side swizzle (= (row>>1)&3)
    const int hs   = (h ^ sw) * 8;      // swizzled chunk offset (u16 units)

    f32x4 acc[4][4];
#pragma unroll
    for (int i = 0; i < 4; ++i)
#pragma unroll
        for (int j = 0; j < 4; ++j)
            acc[i][j] = (f32x4){0.f, 0.f, 0.f, 0.f};

    const int NT = K >> 5;

    // tile = 128 rows x 32 cols bf16 (8 KB). Chunk gc in [0,512): LDS slot
    // gc*16B = (row=gc>>2)*64 + (c=gc&3)*16. Source chunk = c ^ ((row>>1)&3)
    // = (lane&3) ^ ((lane>>3)&3) — row-local permute, coalescing intact.
    // 4 VMEM/thread/tile (A2 + B2).
    const int csrc = ((lane & 3) ^ ((lane >> 3) & 3)) * 8;  // u16 offset in row

    auto stageA = [&](int t, int buf) {
#pragma unroll
        for (int q = 0; q < 2; ++q) {
            int gc = (wid * 2 + q) * 64 + lane;
            int r = gc >> 2;
            int grow = m0 + r; grow = grow < M ? grow : M - 1;
            const u16* src = A + (size_t)grow * lda + (t << 5) + csrc;
            gload_lds16(src, &lA[buf][(wid * 2 + q) * 512]);
        }
    };
    auto stageB = [&](int t, int buf) {
#pragma unroll
        for (int q = 0; q < 2; ++q) {
            int gc = (wid * 2 + q) * 64 + lane;
            int r = gc >> 2;
            const u16* src = Bt + (size_t)(n0 + r) * ldb + (t << 5) + csrc;
            gload_lds16(src, &lB[buf][(wid * 2 + q) * 512]);
        }
    };

    // prologue: tiles 0 and 1 in flight (8 outstanding VMEM/thread)
    stageA(0, 0); stageB(0, 0);
    stageA(1, 1); stageB(1, 1);

    for (int t = 0; t < NT; ++t) {
        const int buf = t % 3;
        if (t + 1 < NT) {
            // outstanding: tiles t, t+1 (8). Wait tile t; t+1 keeps flying.
            asm volatile("s_waitcnt vmcnt(4)" ::: "memory");
        } else {
            asm volatile("s_waitcnt vmcnt(0)" ::: "memory");
        }
        __builtin_amdgcn_sched_barrier(0);
        __builtin_amdgcn_s_barrier();         // tile t visible; (t-1)%3 free
        __builtin_amdgcn_sched_barrier(0);

        if (t + 2 < NT) {                     // stage into (t+2)%3 = (t-1)%3
            stageA(t + 2, (t + 2) % 3);
            stageB(t + 2, (t + 2) % 3);
        }

        bf16x8 af[4], bfr[4];
#pragma unroll
        for (int i = 0; i < 4; ++i) {
            af[i]  = *(const bf16x8*)&lA[buf][(wm + i * 16 + lr) * 32 + hs];
            bfr[i] = *(const bf16x8*)&lB[buf][(wn + i * 16 + lr) * 32 + hs];
        }
#pragma unroll
        for (int i = 0; i < 4; ++i)
#pragma unroll
            for (int j = 0; j < 4; ++j)
                acc[i][j] = __builtin_amdgcn_mfma_f32_16x16x32_bf16(af[i], bfr[j], acc[i][j], 0, 0, 0);
        // no 2nd barrier: ds_reads retire before next step's barrier via the
        // compiler's lgkmcnt-before-MFMA; buffer reuse is 3 steps away.
    }

    float bv[4] = {0.f, 0.f, 0.f, 0.f};
    if (DOBIAS) {
#pragma unroll
        for (int j = 0; j < 4; ++j) bv[j] = bias[n0 + wn + j * 16 + lr];
    }
    // D layout (m89-verified): col = lane&15, row = 4*(lane>>4) + reg
#pragma unroll
    for (int i = 0; i < 4; ++i) {
#pragma unroll
        for (int rj = 0; rj < 4; ++rj) {
            int grow = m0 + wm + i * 16 + 4 * h + rj;
            if (grow >= M) continue;
            size_t ro = (size_t)grow * ldc;
            size_t xo = 0, lo = 0;
            if (DORES) {
                int nn = grow % Nn;
                xo = (size_t)grow * 1024;      // XS row (bf16 x in cols 0..511)
                lo = (size_t)nn * 512;
            }
#pragma unroll
            for (int j = 0; j < 4; ++j) {
                int gcol = n0 + wn + j * 16 + lr;
                float v = acc[i][j][rj] + bv[j];
                if (DOSILU) v = v * __builtin_amdgcn_rcpf(1.f + __expf(-v));
                if (DORES)
                    v += bf2f(xres[xo + gcol]) + lat[lo + gcol] + ub2v[gcol];
                if (OUTF32) Cf[ro + gcol] = v;
                else        Cb[ro + gcol] = f2bf(v);
            }
        }
    }
}

// ---------------------------------------------------------------------------
// S[row] = (1/8) * sum_k silu(c_projb[row] + n_proj[b, knn[n,k]])
// (mb1 folded into c_proj via G1 bias.)  Writes cols 512.. of XS.
// ---------------------------------------------------------------------------
__global__ void gather_silu_mean(const u16* __restrict__ P, const int* __restrict__ knn,
                                 u16* __restrict__ XS, int Nn, int M)
{
    int wid = threadIdx.x >> 6, lane = threadIdx.x & 63;
    int row = blockIdx.x * 4 + wid;
    if (row >= M) return;
    int b = row / Nn, n = row - b * Nn;
    int c0 = lane * 8;

    int idx[8];
#pragma unroll
    for (int k = 0; k < 8; ++k) idx[k] = knn[n * 8 + k];

    us8 cu = *(const us8*)(P + (size_t)row * 1024 + c0);
    const u16* Pn = P + (size_t)b * Nn * 1024 + 512 + c0;
    us8 nb[8];
#pragma unroll
    for (int k = 0; k < 8; ++k) nb[k] = *(const us8*)(Pn + (size_t)idx[k] * 1024);

    float base[8], accv[8];
#pragma unroll
    for (int i = 0; i < 8; ++i) { base[i] = bf2f(cu[i]); accv[i] = 0.f; }

#pragma unroll
    for (int k = 0; k < 8; ++k)
#pragma unroll
        for (int i = 0; i < 8; ++i) {
            float pv = base[i] + bf2f(nb[k][i]);
            accv[i] += pv * __builtin_amdgcn_rcpf(1.f + __expf(-pv));
        }

    us8 o;
#pragma unroll
    for (int i = 0; i < 8; ++i) o[i] = f2bf(accv[i] * 0.125f);
    *(us8*)(XS + (size_t)row * 1024 + 512 + c0) = o;
}

// ---------------------------------------------------------------------------
// LN: reads bf16 pre-LN rows (Yt), writes f32 output Y.
// ---------------------------------------------------------------------------
__global__ void ln_fuse(const u16* __restrict__ Yt, float* __restrict__ Y,
                        const float* __restrict__ g, const float* __restrict__ bta,
                        int M)
{
    int wid = threadIdx.x >> 6, lane = threadIdx.x & 63;
    int row = blockIdx.x * 4 + wid;
    if (row >= M) return;
    int c0 = lane * 8;

    us8 u = *(const us8*)(Yt + (size_t)row * 512 + c0);
    float v[8];
#pragma unroll
    for (int i = 0; i < 8; ++i) v[i] = bf2f(u[i]);

    float s = 0.f;
#pragma unroll
    for (int i = 0; i < 8; ++i) s += v[i];
#pragma unroll
    for (int off = 32; off > 0; off >>= 1) s += __shfl_xor(s, off, 64);
    float mu = s * (1.f / 512.f);

    float q = 0.f;
#pragma unroll
    for (int i = 0; i < 8; ++i) { float d = v[i] - mu; q += d * d; }
#pragma unroll
    for (int off = 32; off > 0; off >>= 1) q += __shfl_xor(q, off, 64);
    float inv = rsqrtf(q * (1.f / 512.f) + 1e-5f);

    float* yr = Y + (size_t)row * 512 + c0;
#pragma unroll
    for (int i = 0; i < 8; ++i) yr[i] = (v[i] - mu) * inv * g[c0 + i] + bta[c0 + i];
}

extern "C" void kernel_launch(void* const* d_in, const int* in_sizes, int n_in,
                              void* d_out, int out_size, void* d_ws, size_t ws_size,
                              hipStream_t stream)
{
    const float* x   = (const float*)d_in[0];
    const float* lat = (const float*)d_in[1];
    const int*   knn = (const int*)d_in[2];
    const float* mW1 = (const float*)d_in[3];
    const float* mb1 = (const float*)d_in[4];
    const float* mW2 = (const float*)d_in[5];
    const float* mb2 = (const float*)d_in[6];
    const float* uW1 = (const float*)d_in[7];
    const float* ub1 = (const float*)d_in[8];
    const float* uW2 = (const float*)d_in[9];
    const float* ub2 = (const float*)d_in[10];
    const float* lng = (const float*)d_in[11];
    const float* lnb = (const float*)d_in[12];

    const int Nn = 10242;
    const int M  = 4 * Nn;       // 40968

    char* ws = (char*)d_ws;
    u16* BT1 = (u16*)ws; ws += (size_t)1024 * 512 * 2;
    u16* BTx = (u16*)ws; ws += (size_t)512 * 1024 * 2;
    u16* BT4 = (u16*)ws; ws += (size_t)512 * 512 * 2;
    u16* A_w = (u16*)ws; ws += (size_t)512 * 512 * 2;
    u16* B_w = (u16*)ws; ws += (size_t)512 * 512 * 2;
    float* bias1024 = (float*)ws; ws += 1024 * 4;
    float* biasx    = (float*)ws; ws += 512 * 4;
    u16* XS = (u16*)ws; ws += (size_t)M * 1024 * 2;    // [x_bf16 | S]
    u16* P  = (u16*)ws; ws += (size_t)M * 1024 * 2;    // [c_proj+mb1 | n_proj]
    u16* T  = (u16*)ws; ws += (size_t)M * 512 * 2;     // silu(u-pre)
    u16* Yt = P;                    // P dead after gather; reuse for pre-LN
    float* Y = (float*)d_out;

    const int MB = (M + 127) / 128;  // 321

    prep_weights<<<2048, 256, 0, stream>>>(mW1, mW2, uW1, uW2, mb1,
                                           BT1, BT4, A_w, B_w, BTx, bias1024);
    prep_biasx<<<128, 256, 0, stream>>>(ub1, mb2, uW1, biasx);
    cast_x<<<(M * 512 / 4 + 255) / 256, 256, 0, stream>>>(x, XS, M * 512 / 4);

    // Wc^T -> BTx cols 512..1023  (M=512, N=512, K=512)
    gemm_bt<0, 0, 0, 0><<<dim3(4, 4), 256, 0, stream>>>(
        A_w, 512, B_w, 512, BTx + 512, nullptr, 1024,
        nullptr, nullptr, nullptr, nullptr, 0, 512, 512);

    // G1: P = x @ [mW1_top | mW1_bot] + [mb1 | 0]   (M x 1024, K=512)
    gemm_bt<0, 0, 1, 0><<<dim3(8, MB), 256, 0, stream>>>(
        XS, 1024, BT1, 512, P, nullptr, 1024,
        bias1024, nullptr, nullptr, nullptr, 0, M, 512);

    gather_silu_mean<<<(M + 3) / 4, 256, 0, stream>>>(P, knn, XS, Nn, M);

    // Gx: T = silu([x|S] @ [uW1_top; Wc] + biasx)   (M x 512, K=1024)
    gemm_bt<0, 1, 1, 0><<<dim3(4, MB), 256, 0, stream>>>(
        XS, 1024, BTx, 1024, T, nullptr, 512,
        biasx, nullptr, nullptr, nullptr, 0, M, 1024);

    // G4: Yt = bf16(T @ uW2 + x + lat + ub2)   (pre-LN, bf16 into P's buffer)
    gemm_bt<0, 0, 0, 1><<<dim3(4, MB), 256, 0, stream>>>(
        T, 512, BT4, 512, Yt, nullptr, 512,
        nullptr, XS, lat, ub2, Nn, M, 512);

    ln_fuse<<<(M + 3) / 4, 256, 0, stream>>>(Yt, Y, lng, lnb, M);
}